// Round 8
// baseline (9217.393 us; speedup 1.0000x reference)
//
#include <hip/hip_runtime.h>
#include <math.h>

// resRNN forward: N=256, L=1024, inp=521 (=8 x + 1 storage + 512 hx), HID=512, OUT=1.
// Round 8: base = round 6 (best: 7.43 ms; LDS broadcast beat round 7's readlane).
// Single change: streamed W1 rows are packed ROUNDED bf16 (2 rows/dword, 8 rows
// per dwordx4) -> streamed bytes/step/CU 640 KB -> 319 KB, halving the dominant
// L2-port term (~11.4 K -> ~5.7 K cyc of the 17.4 K step). Unpack is 1 VALU
// op/row: lo = pk<<16, hi = pk & 0xffff0000 are directly the fp32 bit patterns.
// Residency: rows [0,128) fp32 AGPR (v_accvgpr asm, proven spill-free),
// [128,204) fp32 LDS (152 KB), [204,208) fp32 pinned arch VGPRs, [208,520)
// streamed bf16 (39 uint4 chunks of 8 rows), row 520 fp32 tail VGPR.
// Precision: streamed rows are hx-weights (|hx|<1, |W1|~0.05); rne-bf16 error
// ~4e-4/step pre-tanh vs current absmax 0.0156.

constexpr int kN   = 256;
constexpr int kL   = 1024;
constexpr int kHin = 8;
constexpr int kHid = 512;
constexpr int kInp = kHin + 1 + kHid;        // 521
constexpr int kBlk = 512;

constexpr int RAGP  = 128;                   // fp32 rows in AGPRs
constexpr int NAGRP = RAGP / 8;              // 16 groups of 8 rows
constexpr int RLDS  = 76;                    // fp32 rows in LDS (152 KB)
constexpr int REXT  = 4;                     // fp32 rows in pinned arch VGPRs
constexpr int RSTR  = RAGP + RLDS + REXT;    // 208: first streamed row
constexpr int NSC   = 39;                    // streamed chunks of 8 bf16 rows
static_assert(RSTR + 8 * NSC + 1 == kInp, "row partition must cover 521 rows");

// Packed streamed weights: g_w1p[c*512 + j] holds rows RSTR+8c..RSTR+8c+7 of
// column j as 4 dwords, each dword = bf16(even row) | bf16(odd row)<<16.
__device__ uint4 g_w1p[NSC * kHid];

__device__ __forceinline__ unsigned bf16rne(float f) {
  const unsigned x = __float_as_uint(f);
  return (x + 0x7fffu + ((x >> 16) & 1u)) >> 16;  // round-to-nearest-even
}

__global__ void repack_w1(const float* __restrict__ W1) {
  const int idx = blockIdx.x * 256 + threadIdx.x;
  if (idx >= NSC * kHid) return;
  const int c = idx >> 9;          // chunk
  const int j = idx & (kHid - 1);  // column
  const int r = RSTR + 8 * c;
  uint4 pk;
  pk.x = bf16rne(W1[(size_t)(r + 0) * kHid + j]) | (bf16rne(W1[(size_t)(r + 1) * kHid + j]) << 16);
  pk.y = bf16rne(W1[(size_t)(r + 2) * kHid + j]) | (bf16rne(W1[(size_t)(r + 3) * kHid + j]) << 16);
  pk.z = bf16rne(W1[(size_t)(r + 4) * kHid + j]) | (bf16rne(W1[(size_t)(r + 5) * kHid + j]) << 16);
  pk.w = bf16rne(W1[(size_t)(r + 6) * kHid + j]) | (bf16rne(W1[(size_t)(r + 7) * kHid + j]) << 16);
  g_w1p[idx] = pk;
}

__global__
__attribute__((amdgpu_flat_work_group_size(kBlk, kBlk)))
__attribute__((amdgpu_waves_per_eu(2, 2)))
void resrnn_fwd(const float* __restrict__ x, const float* __restrict__ W1,
                const float* __restrict__ b1, const float* __restrict__ W2,
                const float* __restrict__ b2, float* __restrict__ out) {
  // inps: [0..7]=x_t, [8]=s_t, [9..520]=hx_{t-1}  (single batch)
  __shared__ __align__(16) float inps[kInp + 3];
  __shared__ float wlds[RLDS][kHid];   // W1 rows [RAGP, RAGP+RLDS), 152 KB
  __shared__ __align__(16) float red[8];

  const int j = threadIdx.x;           // hidden column 0..511
  const int n = blockIdx.x;            // batch element (1 per block)

  const float b2v = b2[0];
  const float w2j = W2[j];
  const float b1j = b1[j];

  float* const outp = out;                        // (N,L,1) flat
  float* const stor = out + (size_t)kN * kL;      // implied_storage

  const float* xn = x + (size_t)n * kL * kHin;

  const float* const wj  = W1 + j;                // column j, stride kHid
  const uint4* const wpk = g_w1p + j;             // packed streamed, stride 512 uint4

  // ---- one-time W1 cache fill: rows [0,RAGP) -> AGPRs ----
  float areg[RAGP];
  #pragma unroll
  for (int r = 0; r < RAGP; ++r) {
    const float v = wj[(size_t)r * kHid];
    asm volatile("v_accvgpr_write_b32 %0, %1" : "=a"(areg[r]) : "v"(v));
  }
  // rows [RAGP, RAGP+RLDS) -> LDS
  for (int r = 0; r < RLDS; ++r) wlds[r][j] = wj[(size_t)(RAGP + r) * kHid];
  // rows 204..207 + tail row 520 -> pinned arch VGPRs, loaded once
  float wex0 = wj[(size_t)(RAGP + RLDS + 0) * kHid];
  float wex1 = wj[(size_t)(RAGP + RLDS + 1) * kHid];
  float wex2 = wj[(size_t)(RAGP + RLDS + 2) * kHid];
  float wex3 = wj[(size_t)(RAGP + RLDS + 3) * kHid];
  float wtail = wj[(size_t)(kInp - 1) * kHid];
  asm volatile("" : "+v"(wex0), "+v"(wex1), "+v"(wex2), "+v"(wex3), "+v"(wtail));

  // ---- init: hx = 0, s_0 = x_0[0] ----
  inps[kHin + 1 + j] = 0.f;
  float s = xn[0];
  if (j < kHin) inps[j] = xn[j];
  if (j == 8)   inps[kHin] = s;
  if (j == 0)   stor[(size_t)n * kL] = s;
  __syncthreads();

  for (int t = 0; t < kL; ++t) {
    float a0 = b1j;   // fma chain A (even rows)
    float c0 = 0.f;   // fma chain B (odd rows)

    // ---- rows [0, RAGP): weights in AGPRs; 16 groups of 8 rows.
    // Inputs for group g+1 loaded BEFORE group g's asm block so ds_read
    // latency hides under the previous group's reads+FMAs.
    float4 nx0 = *reinterpret_cast<const float4*>(&inps[0]);
    float4 nx1 = *reinterpret_cast<const float4*>(&inps[4]);
    #pragma unroll
    for (int g = 0; g < NAGRP; ++g) {
      const float4 u0 = nx0, u1 = nx1;
      if (g + 1 < NAGRP) {
        nx0 = *reinterpret_cast<const float4*>(&inps[8 * (g + 1)]);
        nx1 = *reinterpret_cast<const float4*>(&inps[8 * (g + 1) + 4]);
      }
      float w0, w1, w2, w3, w4, w5, w6, w7;
      asm volatile(
          "v_accvgpr_read_b32 %0, %8\n\t"
          "v_accvgpr_read_b32 %1, %9\n\t"
          "v_accvgpr_read_b32 %2, %10\n\t"
          "v_accvgpr_read_b32 %3, %11\n\t"
          "v_accvgpr_read_b32 %4, %12\n\t"
          "v_accvgpr_read_b32 %5, %13\n\t"
          "v_accvgpr_read_b32 %6, %14\n\t"
          "v_accvgpr_read_b32 %7, %15"
          : "=v"(w0), "=v"(w1), "=v"(w2), "=v"(w3),
            "=v"(w4), "=v"(w5), "=v"(w6), "=v"(w7)
          : "a"(areg[8 * g + 0]), "a"(areg[8 * g + 1]),
            "a"(areg[8 * g + 2]), "a"(areg[8 * g + 3]),
            "a"(areg[8 * g + 4]), "a"(areg[8 * g + 5]),
            "a"(areg[8 * g + 6]), "a"(areg[8 * g + 7]));
      a0 = fmaf(u0.x, w0, a0); c0 = fmaf(u0.y, w1, c0);
      a0 = fmaf(u0.z, w2, a0); c0 = fmaf(u0.w, w3, c0);
      a0 = fmaf(u1.x, w4, a0); c0 = fmaf(u1.y, w5, c0);
      a0 = fmaf(u1.z, w6, a0); c0 = fmaf(u1.w, w7, c0);
    }

    // ---- rows [RAGP, RAGP+RLDS): weights in LDS, 4 rows per float4 of inps ----
    #pragma unroll 4
    for (int k = 0; k < RLDS; k += 4) {
      const float4 v = *reinterpret_cast<const float4*>(&inps[RAGP + k]);
      const float wa = wlds[k + 0][j];
      const float wb = wlds[k + 1][j];
      const float wc = wlds[k + 2][j];
      const float wd = wlds[k + 3][j];
      a0 = fmaf(v.x, wa, a0); c0 = fmaf(v.y, wb, c0);
      a0 = fmaf(v.z, wc, a0); c0 = fmaf(v.w, wd, c0);
    }

    // ---- rows 204..207: pinned arch-VGPR weights ----
    {
      const float4 v = *reinterpret_cast<const float4*>(&inps[RAGP + RLDS]);
      a0 = fmaf(v.x, wex0, a0); c0 = fmaf(v.y, wex1, c0);
      a0 = fmaf(v.z, wex2, a0); c0 = fmaf(v.w, wex3, c0);
    }

    // ---- rows [RSTR, 520): streamed packed bf16, one dwordx4 per 8 rows ----
    #pragma unroll 8
    for (int c = 0; c < NSC; ++c) {
      const uint4 pk = wpk[(size_t)c * kHid];
      const int kb = RSTR + 8 * c;
      const float4 va = *reinterpret_cast<const float4*>(&inps[kb]);
      const float4 vb = *reinterpret_cast<const float4*>(&inps[kb + 4]);
      a0 = fmaf(va.x, __uint_as_float(pk.x << 16),        a0);
      c0 = fmaf(va.y, __uint_as_float(pk.x & 0xffff0000u), c0);
      a0 = fmaf(va.z, __uint_as_float(pk.y << 16),        a0);
      c0 = fmaf(va.w, __uint_as_float(pk.y & 0xffff0000u), c0);
      a0 = fmaf(vb.x, __uint_as_float(pk.z << 16),        a0);
      c0 = fmaf(vb.y, __uint_as_float(pk.z & 0xffff0000u), c0);
      a0 = fmaf(vb.z, __uint_as_float(pk.w << 16),        a0);
      c0 = fmaf(vb.w, __uint_as_float(pk.w & 0xffff0000u), c0);
    }
    a0 = fmaf(inps[kInp - 1], wtail, a0);  // tail row 520 (fp32)

    const float h = tanhf(a0 + c0);

    // ---- out = hx_new . W2 + b2 : wave shuffle reduce, then LDS combine ----
    float p = h * w2j;
    #pragma unroll
    for (int off = 32; off > 0; off >>= 1) p += __shfl_down(p, off, 64);
    const int wid = j >> 6;
    if ((j & 63) == 0) red[wid] = p;
    __syncthreads();  // barrier A: all inps reads done; red[] populated

    const float4 r0 = *reinterpret_cast<const float4*>(&red[0]);
    const float4 r1 = *reinterpret_cast<const float4*>(&red[4]);
    const float o = (((r0.x + r0.y) + (r0.z + r0.w)) +
                     ((r1.x + r1.y) + (r1.z + r1.w))) + b2v;  // same in all threads
    if (j == 0) outp[(size_t)n * kL + t] = o;

    // ---- stage step t+1: hx, x, s = s + x_{t+1}[0] - out_t ----
    inps[kHin + 1 + j] = h;
    if (t + 1 < kL) {
      const float* xr = xn + (size_t)(t + 1) * kHin;
      s += xr[0] - o;  // replicated identically across threads
      if (j < kHin) inps[j] = xr[j];
      if (j == 8)   inps[kHin] = s;
      if (j == 0)   stor[(size_t)n * kL + t + 1] = s;
    }
    __syncthreads();  // barrier B: next-step inp fully staged
  }
}

extern "C" void kernel_launch(void* const* d_in, const int* in_sizes, int n_in,
                              void* d_out, int out_size, void* d_ws, size_t ws_size,
                              hipStream_t stream) {
  const float* x  = (const float*)d_in[0];
  const float* W1 = (const float*)d_in[1];
  const float* b1 = (const float*)d_in[2];
  const float* W2 = (const float*)d_in[3];
  const float* b2 = (const float*)d_in[4];
  float* out = (float*)d_out;

  // one-time (per launch) repack of streamed W1 rows into packed rne-bf16 form
  {
    const int total = NSC * kHid;                 // 19968
    dim3 g((total + 255) / 256), b(256);
    hipLaunchKernelGGL(repack_w1, g, b, 0, stream, W1);
  }

  dim3 grid(kN);          // 256 blocks -> 1 batch element per block, all CUs
  dim3 block(kBlk);       // 512 threads = 8 waves
  hipLaunchKernelGGL(resrnn_fwd, grid, block, 0, stream, x, W1, b1, W2, b2, out);
}

// Round 9
// 7310.719 us; speedup vs baseline: 1.2608x; 1.2608x over previous
//
#include <hip/hip_runtime.h>
#include <math.h>

// resRNN forward: N=256, L=1024, inp=521 (=8 x + 1 storage + 512 hx), HID=512, OUT=1.
// Round 9: model re-fit. R6 (best, 7.43 ms) is ADDITIVE-phase latency-bound at
// 2 waves/SIMD: stream 10.5K + LDS 4K + VALU 2.5K + tail 2K ~= 19.5K cyc/step,
// phases serial (R7/R8 falsified all byte/instr-count models). Fix the
// structure: split-K, 1024 threads (16 waves, 4/SIMD), 256 blocks.
// Thread (j, half) accumulates rows [0,260) or [260,521) of column j.
// Per-CU work identical to R6 (same fma / LDS-instr / streamed bytes); only
// the partition changes: per-wave chains halve, waves/SIMD double -> phases
// overlap. Residency per thread (128-reg budget at 4 waves/EU): 64 AGPR rows,
// 32 LDS rows, 164 streamed fp32 rows (41 float4 chunks); half1 + row 520.
// bf16 (R8) fully reverted: absmax returns to ~0.0156.

constexpr int kN   = 256;
constexpr int kL   = 1024;
constexpr int kHin = 8;
constexpr int kHid = 512;
constexpr int kInp = kHin + 1 + kHid;  // 521
constexpr int kBlk = 1024;

constexpr int AGP_H  = 64;    // AGPR rows per half-thread
constexpr int NAG_H  = AGP_H / 8;      // 8 asm groups
constexpr int LDS_H  = 32;    // LDS rows per half
constexpr int NSC_H  = 41;    // streamed float4 chunks per half (164 rows)
constexpr int H0     = 260;   // half0 rows [0,260), half1 [260,521)
static_assert(AGP_H + LDS_H + 4 * NSC_H == H0, "half0 partition");
static_assert(H0 + AGP_H + LDS_H + 4 * NSC_H + 1 == kInp, "half1 partition");

// Streamed weights packed 4-rows-per-float4 per column:
// g_w1p[(c)*512 + j], c in [0,41) -> rows 96+4c (half0); c in [41,82) -> rows 356+4(c-41).
__device__ __align__(16) float4 g_w1p[2 * NSC_H * kHid];

__global__ void repack_w1(const float* __restrict__ W1) {
  const int idx = blockIdx.x * 256 + threadIdx.x;
  if (idx >= 2 * NSC_H * kHid) return;
  const int c = idx >> 9;
  const int j = idx & (kHid - 1);
  const int r = (c < NSC_H) ? (AGP_H + LDS_H + 4 * c)
                            : (H0 + AGP_H + LDS_H + 4 * (c - NSC_H));
  float4 v;
  v.x = W1[(size_t)(r + 0) * kHid + j];
  v.y = W1[(size_t)(r + 1) * kHid + j];
  v.z = W1[(size_t)(r + 2) * kHid + j];
  v.w = W1[(size_t)(r + 3) * kHid + j];
  g_w1p[idx] = v;
}

__global__
__attribute__((amdgpu_flat_work_group_size(kBlk, kBlk)))
__attribute__((amdgpu_waves_per_eu(4, 4)))
void resrnn_fwd(const float* __restrict__ x, const float* __restrict__ W1,
                const float* __restrict__ b1, const float* __restrict__ W2,
                const float* __restrict__ b2, float* __restrict__ out) {
  // inps: [0..7]=x_t, [8]=s_t, [9..520]=hx_{t-1}
  __shared__ __align__(16) float inps[kInp + 3];
  __shared__ float wlds[2 * LDS_H][kHid];   // 64 rows, 131 KB
  __shared__ float part[2][kHid];           // cross-half partials, 4 KB
  __shared__ __align__(16) float red[8];

  const int tid  = threadIdx.x;
  const int j    = tid & (kHid - 1);   // hidden column
  const int half = tid >> 9;           // K-half: 0 -> rows [0,260), 1 -> [260,521)
  const int n    = blockIdx.x;         // batch element

  const int base = half ? H0 : 0;      // first row of this half

  const float b2v = b2[0];
  const float w2j = W2[j];
  const float b1j = b1[j];

  float* const outp = out;
  float* const stor = out + (size_t)kN * kL;

  const float* xn = x + (size_t)n * kL * kHin;

  const float* const wj  = W1 + j;                              // column j
  const float4* const wpk = g_w1p + (size_t)(half * NSC_H) * kHid + j;

  // ---- one-time fill: rows [base, base+64) -> AGPRs ----
  float areg[AGP_H];
  #pragma unroll
  for (int r = 0; r < AGP_H; ++r) {
    const float v = wj[(size_t)(base + r) * kHid];
    asm volatile("v_accvgpr_write_b32 %0, %1" : "=a"(areg[r]) : "v"(v));
  }
  // rows [base+64, base+96) -> LDS
  for (int r = 0; r < LDS_H; ++r)
    wlds[half * LDS_H + r][j] = wj[(size_t)(base + AGP_H + r) * kHid];
  // row 520 (half1 only) -> pinned arch VGPR
  float wtail = wj[(size_t)(kInp - 1) * kHid];
  asm volatile("" : "+v"(wtail));

  // ---- init: hx = 0, s_0 = x_0[0] ----
  if (!half) inps[kHin + 1 + j] = 0.f;
  float s = xn[0];
  if (half && j < kHin) inps[j] = xn[j];
  if (half && j == kHin) inps[kHin] = s;
  if (tid == 0) stor[(size_t)n * kL] = s;
  __syncthreads();

  for (int t = 0; t < kL; ++t) {
    float a0 = half ? 0.f : b1j;   // fma chain A
    float c0 = 0.f;                // fma chain B

    // ---- rows [base, base+64): AGPR weights; 8 groups of 8 rows.
    float4 nx0 = *reinterpret_cast<const float4*>(&inps[base]);
    float4 nx1 = *reinterpret_cast<const float4*>(&inps[base + 4]);
    #pragma unroll
    for (int g = 0; g < NAG_H; ++g) {
      const float4 u0 = nx0, u1 = nx1;
      if (g + 1 < NAG_H) {
        nx0 = *reinterpret_cast<const float4*>(&inps[base + 8 * (g + 1)]);
        nx1 = *reinterpret_cast<const float4*>(&inps[base + 8 * (g + 1) + 4]);
      }
      float w0, w1, w2, w3, w4, w5, w6, w7;
      asm volatile(
          "v_accvgpr_read_b32 %0, %8\n\t"
          "v_accvgpr_read_b32 %1, %9\n\t"
          "v_accvgpr_read_b32 %2, %10\n\t"
          "v_accvgpr_read_b32 %3, %11\n\t"
          "v_accvgpr_read_b32 %4, %12\n\t"
          "v_accvgpr_read_b32 %5, %13\n\t"
          "v_accvgpr_read_b32 %6, %14\n\t"
          "v_accvgpr_read_b32 %7, %15"
          : "=v"(w0), "=v"(w1), "=v"(w2), "=v"(w3),
            "=v"(w4), "=v"(w5), "=v"(w6), "=v"(w7)
          : "a"(areg[8 * g + 0]), "a"(areg[8 * g + 1]),
            "a"(areg[8 * g + 2]), "a"(areg[8 * g + 3]),
            "a"(areg[8 * g + 4]), "a"(areg[8 * g + 5]),
            "a"(areg[8 * g + 6]), "a"(areg[8 * g + 7]));
      a0 = fmaf(u0.x, w0, a0); c0 = fmaf(u0.y, w1, c0);
      a0 = fmaf(u0.z, w2, a0); c0 = fmaf(u0.w, w3, c0);
      a0 = fmaf(u1.x, w4, a0); c0 = fmaf(u1.y, w5, c0);
      a0 = fmaf(u1.z, w6, a0); c0 = fmaf(u1.w, w7, c0);
    }

    // ---- rows [base+64, base+96): LDS weights ----
    #pragma unroll 4
    for (int u = 0; u < LDS_H; u += 4) {
      const float4 v = *reinterpret_cast<const float4*>(&inps[base + AGP_H + u]);
      const float wa = wlds[half * LDS_H + u + 0][j];
      const float wb = wlds[half * LDS_H + u + 1][j];
      const float wc = wlds[half * LDS_H + u + 2][j];
      const float wd = wlds[half * LDS_H + u + 3][j];
      a0 = fmaf(v.x, wa, a0); c0 = fmaf(v.y, wb, c0);
      a0 = fmaf(v.z, wc, a0); c0 = fmaf(v.w, wd, c0);
    }

    // ---- rows [base+96, base+260): streamed fp32, 41 float4 chunks ----
    const int sbase = base + AGP_H + LDS_H;
    #pragma unroll 4
    for (int c = 0; c < NSC_H; ++c) {
      const float4 wv = wpk[(size_t)c * kHid];
      const float4 v  = *reinterpret_cast<const float4*>(&inps[sbase + 4 * c]);
      a0 = fmaf(v.x, wv.x, a0); c0 = fmaf(v.y, wv.y, c0);
      a0 = fmaf(v.z, wv.z, a0); c0 = fmaf(v.w, wv.w, c0);
    }
    if (half) a0 = fmaf(inps[kInp - 1], wtail, a0);  // tail row 520

    part[half][j] = a0 + c0;
    __syncthreads();  // barrier 2: partials ready; all inps reads done

    const float h = tanhf(part[0][j] + part[1][j]);

    // stage next-step inputs that don't depend on o
    if (!half) inps[kHin + 1 + j] = h;
    const float* xr = xn + (size_t)(t + 1) * kHin;
    if (t + 1 < kL && half && j < kHin) inps[j] = xr[j];

    // ---- out = h . W2 + b2 : half0 waves shuffle-reduce ----
    if (!half) {
      float p = h * w2j;
      #pragma unroll
      for (int off = 32; off > 0; off >>= 1) p += __shfl_down(p, off, 64);
      if ((tid & 63) == 0) red[tid >> 6] = p;
    }
    __syncthreads();  // barrier 3: red ready; h/x staged

    const float4 r0 = *reinterpret_cast<const float4*>(&red[0]);
    const float4 r1 = *reinterpret_cast<const float4*>(&red[4]);
    const float o = (((r0.x + r0.y) + (r0.z + r0.w)) +
                     ((r1.x + r1.y) + (r1.z + r1.w))) + b2v;  // same in all threads
    if (tid == 0) outp[(size_t)n * kL + t] = o;

    if (t + 1 < kL) {
      s += xr[0] - o;  // replicated identically across all threads
      if (half && j == kHin) inps[kHin] = s;
      if (tid == 0) stor[(size_t)n * kL + t + 1] = s;
    }
    __syncthreads();  // barrier 1 (loop top): next-step inps fully staged
  }
}

extern "C" void kernel_launch(void* const* d_in, const int* in_sizes, int n_in,
                              void* d_out, int out_size, void* d_ws, size_t ws_size,
                              hipStream_t stream) {
  const float* x  = (const float*)d_in[0];
  const float* W1 = (const float*)d_in[1];
  const float* b1 = (const float*)d_in[2];
  const float* W2 = (const float*)d_in[3];
  const float* b2 = (const float*)d_in[4];
  float* out = (float*)d_out;

  // one-time (per launch) repack of streamed W1 rows into float4-per-column form
  {
    const int total = 2 * NSC_H * kHid;           // 41984
    dim3 g((total + 255) / 256), b(256);
    hipLaunchKernelGGL(repack_w1, g, b, 0, stream, W1);
  }

  dim3 grid(kN);          // 256 blocks, 1 batch each, all 256 CUs
  dim3 block(kBlk);       // 1024 threads = 16 waves = 4 waves/SIMD
  hipLaunchKernelGGL(resrnn_fwd, grid, block, 0, stream, x, W1, b1, W2, b2, out);
}

// Round 10
// 5589.199 us; speedup vs baseline: 1.6491x; 1.3080x over previous
//
#include <hip/hip_runtime.h>
#include <hip/hip_fp16.h>
#include <math.h>

// resRNN forward: N=256, L=1024, inp=521 (=8 x + 1 storage + 512 hx), HID=512, OUT=1.
// Round 10: R0/R6/R9 all fit the same HW ceiling: weight-stream from L2 at
// ~38.4 B/cyc/CU (R9 proved full phase overlap: step time == stream term).
// Residency is maxed (256 KB RF + 131 KB LDS of W1). Only lever left is the
// byte count -> streamed rows move to fp16 (rne, rel err 2^-12; R8's bf16 at
// 2^-9 gave absmax 0.10 and still passed; fp16 is 8x tighter).
// Structure = R9 (split-K, 1024 thr, 16 waves, 4/SIMD, 256 blocks) unchanged.
// Per half: rows [base,base+64) fp32 AGPR, [base+64,base+96) fp32 LDS,
// [base+96,base+100) fp32 pinned VGPR, [base+100,base+260) fp16 streamed
// (20 uint4 chunks of 8 rows); half1 adds fp32 tail row 520.
// Streamed bytes/step/CU: 672 KB -> 336 KB.

constexpr int kN   = 256;
constexpr int kL   = 1024;
constexpr int kHin = 8;
constexpr int kHid = 512;
constexpr int kInp = kHin + 1 + kHid;  // 521
constexpr int kBlk = 1024;

constexpr int AGP_H = 64;              // AGPR rows per half-thread
constexpr int NAG_H = AGP_H / 8;       // 8 asm groups
constexpr int LDS_H = 32;              // LDS rows per half
constexpr int EXT_H = 4;               // pinned arch-VGPR rows per half
constexpr int NSC_H = 20;              // streamed uint4 chunks (8 fp16 rows each)
constexpr int H0    = 260;             // half0 rows [0,260), half1 [260,521)
static_assert(AGP_H + LDS_H + EXT_H + 8 * NSC_H == H0, "half0 partition");
static_assert(H0 + AGP_H + LDS_H + EXT_H + 8 * NSC_H + 1 == kInp, "half1 partition");

// Streamed fp16 weights: g_w1p[(half*NSC_H + c)*512 + j] = rows
// base+100+8c .. base+100+8c+7 of column j; dword = even | odd<<16.
__device__ __align__(16) uint4 g_w1p[2 * NSC_H * kHid];

__device__ __forceinline__ unsigned pk2h(float lo, float hi) {
  return (unsigned)__half_as_ushort(__float2half(lo)) |
         ((unsigned)__half_as_ushort(__float2half(hi)) << 16);
}

__global__ void repack_w1(const float* __restrict__ W1) {
  const int idx = blockIdx.x * 256 + threadIdx.x;
  if (idx >= 2 * NSC_H * kHid) return;
  const int c = idx >> 9;          // global chunk (0..39)
  const int j = idx & (kHid - 1);  // column
  const int base = (c < NSC_H) ? 0 : H0;
  const int cc   = (c < NSC_H) ? c : c - NSC_H;
  const int r = base + AGP_H + LDS_H + EXT_H + 8 * cc;
  uint4 pk;
  pk.x = pk2h(W1[(size_t)(r + 0) * kHid + j], W1[(size_t)(r + 1) * kHid + j]);
  pk.y = pk2h(W1[(size_t)(r + 2) * kHid + j], W1[(size_t)(r + 3) * kHid + j]);
  pk.z = pk2h(W1[(size_t)(r + 4) * kHid + j], W1[(size_t)(r + 5) * kHid + j]);
  pk.w = pk2h(W1[(size_t)(r + 6) * kHid + j], W1[(size_t)(r + 7) * kHid + j]);
  g_w1p[idx] = pk;
}

__global__
__attribute__((amdgpu_flat_work_group_size(kBlk, kBlk)))
__attribute__((amdgpu_waves_per_eu(4, 4)))
void resrnn_fwd(const float* __restrict__ x, const float* __restrict__ W1,
                const float* __restrict__ b1, const float* __restrict__ W2,
                const float* __restrict__ b2, float* __restrict__ out) {
  // inps: [0..7]=x_t, [8]=s_t, [9..520]=hx_{t-1}
  __shared__ __align__(16) float inps[kInp + 3];
  __shared__ float wlds[2 * LDS_H][kHid];   // 64 fp32 rows, 131 KB
  __shared__ float part[2][kHid];           // cross-half partials, 4 KB
  __shared__ __align__(16) float red[8];

  const int tid  = threadIdx.x;
  const int j    = tid & (kHid - 1);   // hidden column
  const int half = tid >> 9;           // K-half
  const int n    = blockIdx.x;         // batch element

  const int base = half ? H0 : 0;

  const float b2v = b2[0];
  const float w2j = W2[j];
  const float b1j = b1[j];

  float* const outp = out;
  float* const stor = out + (size_t)kN * kL;

  const float* xn = x + (size_t)n * kL * kHin;

  const float* const wj   = W1 + j;                                  // column j
  const uint4* const wpk  = g_w1p + (size_t)(half * NSC_H) * kHid + j;

  // ---- one-time fill: rows [base, base+64) -> AGPRs ----
  float areg[AGP_H];
  #pragma unroll
  for (int r = 0; r < AGP_H; ++r) {
    const float v = wj[(size_t)(base + r) * kHid];
    asm volatile("v_accvgpr_write_b32 %0, %1" : "=a"(areg[r]) : "v"(v));
  }
  // rows [base+64, base+96) -> LDS
  for (int r = 0; r < LDS_H; ++r)
    wlds[half * LDS_H + r][j] = wj[(size_t)(base + AGP_H + r) * kHid];
  // rows base+96..base+99 -> pinned arch VGPRs; row 520 (half1) tail
  float wex0 = wj[(size_t)(base + AGP_H + LDS_H + 0) * kHid];
  float wex1 = wj[(size_t)(base + AGP_H + LDS_H + 1) * kHid];
  float wex2 = wj[(size_t)(base + AGP_H + LDS_H + 2) * kHid];
  float wex3 = wj[(size_t)(base + AGP_H + LDS_H + 3) * kHid];
  float wtail = wj[(size_t)(kInp - 1) * kHid];
  asm volatile("" : "+v"(wex0), "+v"(wex1), "+v"(wex2), "+v"(wex3), "+v"(wtail));

  // ---- init: hx = 0, s_0 = x_0[0] ----
  if (!half) inps[kHin + 1 + j] = 0.f;
  float s = xn[0];
  if (half && j < kHin) inps[j] = xn[j];
  if (half && j == kHin) inps[kHin] = s;
  if (tid == 0) stor[(size_t)n * kL] = s;
  __syncthreads();

  for (int t = 0; t < kL; ++t) {
    float a0 = half ? 0.f : b1j;   // fma chain A (even rows)
    float c0 = 0.f;                // fma chain B (odd rows)

    // ---- rows [base, base+64): AGPR weights; 8 groups of 8 rows ----
    float4 nx0 = *reinterpret_cast<const float4*>(&inps[base]);
    float4 nx1 = *reinterpret_cast<const float4*>(&inps[base + 4]);
    #pragma unroll
    for (int g = 0; g < NAG_H; ++g) {
      const float4 u0 = nx0, u1 = nx1;
      if (g + 1 < NAG_H) {
        nx0 = *reinterpret_cast<const float4*>(&inps[base + 8 * (g + 1)]);
        nx1 = *reinterpret_cast<const float4*>(&inps[base + 8 * (g + 1) + 4]);
      }
      float w0, w1, w2, w3, w4, w5, w6, w7;
      asm volatile(
          "v_accvgpr_read_b32 %0, %8\n\t"
          "v_accvgpr_read_b32 %1, %9\n\t"
          "v_accvgpr_read_b32 %2, %10\n\t"
          "v_accvgpr_read_b32 %3, %11\n\t"
          "v_accvgpr_read_b32 %4, %12\n\t"
          "v_accvgpr_read_b32 %5, %13\n\t"
          "v_accvgpr_read_b32 %6, %14\n\t"
          "v_accvgpr_read_b32 %7, %15"
          : "=v"(w0), "=v"(w1), "=v"(w2), "=v"(w3),
            "=v"(w4), "=v"(w5), "=v"(w6), "=v"(w7)
          : "a"(areg[8 * g + 0]), "a"(areg[8 * g + 1]),
            "a"(areg[8 * g + 2]), "a"(areg[8 * g + 3]),
            "a"(areg[8 * g + 4]), "a"(areg[8 * g + 5]),
            "a"(areg[8 * g + 6]), "a"(areg[8 * g + 7]));
      a0 = fmaf(u0.x, w0, a0); c0 = fmaf(u0.y, w1, c0);
      a0 = fmaf(u0.z, w2, a0); c0 = fmaf(u0.w, w3, c0);
      a0 = fmaf(u1.x, w4, a0); c0 = fmaf(u1.y, w5, c0);
      a0 = fmaf(u1.z, w6, a0); c0 = fmaf(u1.w, w7, c0);
    }

    // ---- rows [base+64, base+96): LDS fp32 weights ----
    #pragma unroll 4
    for (int u = 0; u < LDS_H; u += 4) {
      const float4 v = *reinterpret_cast<const float4*>(&inps[base + AGP_H + u]);
      const float wa = wlds[half * LDS_H + u + 0][j];
      const float wb = wlds[half * LDS_H + u + 1][j];
      const float wc = wlds[half * LDS_H + u + 2][j];
      const float wd = wlds[half * LDS_H + u + 3][j];
      a0 = fmaf(v.x, wa, a0); c0 = fmaf(v.y, wb, c0);
      a0 = fmaf(v.z, wc, a0); c0 = fmaf(v.w, wd, c0);
    }

    // ---- rows base+96..base+99: pinned arch-VGPR fp32 weights ----
    {
      const float4 v = *reinterpret_cast<const float4*>(&inps[base + AGP_H + LDS_H]);
      a0 = fmaf(v.x, wex0, a0); c0 = fmaf(v.y, wex1, c0);
      a0 = fmaf(v.z, wex2, a0); c0 = fmaf(v.w, wex3, c0);
    }

    // ---- rows [base+100, base+260): streamed fp16, 20 uint4 chunks of 8 rows ----
    const int sbase = base + AGP_H + LDS_H + EXT_H;
    #pragma unroll 4
    for (int c = 0; c < NSC_H; ++c) {
      const uint4 pk = wpk[(size_t)c * kHid];
      const int kb = sbase + 8 * c;
      const float4 va = *reinterpret_cast<const float4*>(&inps[kb]);
      const float4 vb = *reinterpret_cast<const float4*>(&inps[kb + 4]);
      const __half2 p0 = *reinterpret_cast<const __half2*>(&pk.x);
      const __half2 p1 = *reinterpret_cast<const __half2*>(&pk.y);
      const __half2 p2 = *reinterpret_cast<const __half2*>(&pk.z);
      const __half2 p3 = *reinterpret_cast<const __half2*>(&pk.w);
      a0 = fmaf(va.x, __low2float(p0),  a0); c0 = fmaf(va.y, __high2float(p0), c0);
      a0 = fmaf(va.z, __low2float(p1),  a0); c0 = fmaf(va.w, __high2float(p1), c0);
      a0 = fmaf(vb.x, __low2float(p2),  a0); c0 = fmaf(vb.y, __high2float(p2), c0);
      a0 = fmaf(vb.z, __low2float(p3),  a0); c0 = fmaf(vb.w, __high2float(p3), c0);
    }
    if (half) a0 = fmaf(inps[kInp - 1], wtail, a0);  // fp32 tail row 520

    part[half][j] = a0 + c0;
    __syncthreads();  // barrier 2: partials ready; all inps reads done

    const float h = tanhf(part[0][j] + part[1][j]);

    // stage next-step inputs that don't depend on o
    if (!half) inps[kHin + 1 + j] = h;
    const float* xr = xn + (size_t)(t + 1) * kHin;
    if (t + 1 < kL && half && j < kHin) inps[j] = xr[j];

    // ---- out = h . W2 + b2 : half0 waves shuffle-reduce ----
    if (!half) {
      float p = h * w2j;
      #pragma unroll
      for (int off = 32; off > 0; off >>= 1) p += __shfl_down(p, off, 64);
      if ((tid & 63) == 0) red[tid >> 6] = p;
    }
    __syncthreads();  // barrier 3: red ready; h/x staged

    const float4 r0 = *reinterpret_cast<const float4*>(&red[0]);
    const float4 r1 = *reinterpret_cast<const float4*>(&red[4]);
    const float o = (((r0.x + r0.y) + (r0.z + r0.w)) +
                     ((r1.x + r1.y) + (r1.z + r1.w))) + b2v;  // same in all threads
    if (tid == 0) outp[(size_t)n * kL + t] = o;

    if (t + 1 < kL) {
      s += xr[0] - o;  // replicated identically across all threads
      if (half && j == kHin) inps[kHin] = s;
      if (tid == 0) stor[(size_t)n * kL + t + 1] = s;
    }
    __syncthreads();  // barrier 1 (loop top): next-step inps fully staged
  }
}

extern "C" void kernel_launch(void* const* d_in, const int* in_sizes, int n_in,
                              void* d_out, int out_size, void* d_ws, size_t ws_size,
                              hipStream_t stream) {
  const float* x  = (const float*)d_in[0];
  const float* W1 = (const float*)d_in[1];
  const float* b1 = (const float*)d_in[2];
  const float* W2 = (const float*)d_in[3];
  const float* b2 = (const float*)d_in[4];
  float* out = (float*)d_out;

  // one-time (per launch) repack of streamed W1 rows into packed fp16 form
  {
    const int total = 2 * NSC_H * kHid;           // 20480
    dim3 g((total + 255) / 256), b(256);
    hipLaunchKernelGGL(repack_w1, g, b, 0, stream, W1);
  }

  dim3 grid(kN);          // 256 blocks, 1 batch each, all 256 CUs
  dim3 block(kBlk);       // 1024 threads = 16 waves = 4 waves/SIMD
  hipLaunchKernelGGL(resrnn_fwd, grid, block, 0, stream, x, W1, b1, W2, b2, out);
}

// Round 11
// 4688.454 us; speedup vs baseline: 1.9660x; 1.1921x over previous
//
#include <hip/hip_runtime.h>
#include <hip/hip_fp16.h>
#include <math.h>

// resRNN forward: N=256, L=1024, inp=521 (=8 x + 1 storage + 512 hx), HID=512, OUT=1.
// Round 11: R10 landed at 13.1K cyc/step with stream 8.75K and VALU ~8K only
// partially overlapped. Two coupled fixes:
//  (1) v_dot2_f32_f16 (fp16x2 dot, exact f32 accum) for every fp16 row: kills
//      the per-row v_cvt + halves the fma count. Inputs come from hx16[], a
//      1 KB LDS array of rne-packed fp16 pairs of inps, restaged each step by
//      threads 0..227 (reads the already-staged h values; off critical path).
//  (2) LDS-resident weight rows 64 -> 128 (fp16 pairs, same 131 KB), cutting
//      streamed rows 320 -> 256: stream term 336 -> 262 KB/step/CU (~6.8K cyc
//      at the measured 38.4 B/cyc/CU ceiling).
// Partition per half (base = 0 / 260): [base,base+64) fp32 AGPR,
// [base+64,base+128) fp16 LDS pairs, [base+128,base+132) fp32 pinned VGPR,
// [base+132,base+260) fp16 streamed (16 uint4 chunks of 8 rows);
// half1 adds fp32 tail row 520. Structure (split-K, 1024 thr, 4 waves/SIMD,
// 256 blocks) = R9/R10 unchanged.

constexpr int kN   = 256;
constexpr int kL   = 1024;
constexpr int kHin = 8;
constexpr int kHid = 512;
constexpr int kInp = kHin + 1 + kHid;  // 521
constexpr int kBlk = 1024;

constexpr int AGP_H  = 64;             // fp32 AGPR rows per half
constexpr int NAG_H  = AGP_H / 8;      // 8 asm groups
constexpr int LDSP_H = 32;             // fp16 PAIR-rows per half (= 64 rows)
constexpr int EXT_H  = 4;              // fp32 pinned arch-VGPR rows per half
constexpr int NSC_H  = 16;             // streamed uint4 chunks (8 fp16 rows each)
constexpr int H0     = 260;            // half0 rows [0,260), half1 [260,521)
static_assert(AGP_H + 2 * LDSP_H + EXT_H + 8 * NSC_H == H0, "half partition");
static_assert(H0 + AGP_H + 2 * LDSP_H + EXT_H + 8 * NSC_H + 1 == kInp, "full cover");

// Streamed fp16 weights: g_w1p[(half*NSC_H + c)*512 + j] = rows
// base+132+8c .. +7 of column j; each dword = even row | odd row << 16 (rne).
__device__ __align__(16) uint4 g_w1p[2 * NSC_H * kHid];

__device__ __forceinline__ unsigned pk2h_rne(float lo, float hi) {
  return (unsigned)__half_as_ushort(__float2half_rn(lo)) |
         ((unsigned)__half_as_ushort(__float2half_rn(hi)) << 16);
}

// d = a.lo*b.lo + a.hi*b.hi + c   (fp16 products, exact fp32 accumulate)
__device__ __forceinline__ float dot2h(unsigned a, unsigned b, float c) {
  float d;
  asm("v_dot2_f32_f16 %0, %1, %2, %3" : "=v"(d) : "v"(a), "v"(b), "v"(c));
  return d;
}

__global__ void repack_w1(const float* __restrict__ W1) {
  const int idx = blockIdx.x * 256 + threadIdx.x;
  if (idx >= 2 * NSC_H * kHid) return;
  const int c = idx >> 9;          // global chunk (0..31)
  const int j = idx & (kHid - 1);  // column
  const int base = (c < NSC_H) ? 0 : H0;
  const int cc   = (c < NSC_H) ? c : c - NSC_H;
  const int r = base + AGP_H + 2 * LDSP_H + EXT_H + 8 * cc;
  uint4 pk;
  pk.x = pk2h_rne(W1[(size_t)(r + 0) * kHid + j], W1[(size_t)(r + 1) * kHid + j]);
  pk.y = pk2h_rne(W1[(size_t)(r + 2) * kHid + j], W1[(size_t)(r + 3) * kHid + j]);
  pk.z = pk2h_rne(W1[(size_t)(r + 4) * kHid + j], W1[(size_t)(r + 5) * kHid + j]);
  pk.w = pk2h_rne(W1[(size_t)(r + 6) * kHid + j], W1[(size_t)(r + 7) * kHid + j]);
  g_w1p[idx] = pk;
}

__global__
__attribute__((amdgpu_flat_work_group_size(kBlk, kBlk)))
__attribute__((amdgpu_waves_per_eu(4, 4)))
void resrnn_fwd(const float* __restrict__ x, const float* __restrict__ W1,
                const float* __restrict__ b1, const float* __restrict__ W2,
                const float* __restrict__ b2, float* __restrict__ out) {
  // inps: [0..7]=x_t, [8]=s_t, [9..520]=hx_{t-1} (fp32, canonical)
  __shared__ __align__(16) float inps[kInp + 3];
  __shared__ unsigned wlds16[2 * LDSP_H][kHid];  // fp16 pair weights, 131 KB
  __shared__ __align__(8) unsigned hx16[260];    // fp16 pairs of inps[2m],[2m+1]
  __shared__ float part[2][kHid];                // cross-half partials
  __shared__ __align__(16) float red[8];

  const int tid  = threadIdx.x;
  const int j    = tid & (kHid - 1);   // hidden column
  const int half = tid >> 9;           // K-half
  const int n    = blockIdx.x;         // batch element

  const int base = half ? H0 : 0;

  const float b2v = b2[0];
  const float w2j = W2[j];
  const float b1j = b1[j];

  float* const outp = out;
  float* const stor = out + (size_t)kN * kL;

  const float* xn = x + (size_t)n * kL * kHin;

  const float* const wj  = W1 + j;                                  // column j
  const uint4* const wpk = g_w1p + (size_t)(half * NSC_H) * kHid + j;

  // ---- one-time fill: rows [base, base+64) -> AGPRs (fp32) ----
  float areg[AGP_H];
  #pragma unroll
  for (int r = 0; r < AGP_H; ++r) {
    const float v = wj[(size_t)(base + r) * kHid];
    asm volatile("v_accvgpr_write_b32 %0, %1" : "=a"(areg[r]) : "v"(v));
  }
  // rows [base+64, base+128) -> LDS as fp16 pairs
  for (int u = 0; u < LDSP_H; ++u)
    wlds16[half * LDSP_H + u][j] =
        pk2h_rne(wj[(size_t)(base + AGP_H + 2 * u) * kHid],
                 wj[(size_t)(base + AGP_H + 2 * u + 1) * kHid]);
  // rows base+128..base+131 -> pinned arch VGPRs; row 520 (half1) tail
  float wex0 = wj[(size_t)(base + AGP_H + 2 * LDSP_H + 0) * kHid];
  float wex1 = wj[(size_t)(base + AGP_H + 2 * LDSP_H + 1) * kHid];
  float wex2 = wj[(size_t)(base + AGP_H + 2 * LDSP_H + 2) * kHid];
  float wex3 = wj[(size_t)(base + AGP_H + 2 * LDSP_H + 3) * kHid];
  float wtail = wj[(size_t)(kInp - 1) * kHid];
  asm volatile("" : "+v"(wex0), "+v"(wex1), "+v"(wex2), "+v"(wex3), "+v"(wtail));

  // ---- init: hx = 0, s_0 = x_0[0] ----
  if (!half) inps[kHin + 1 + j] = 0.f;
  float s = xn[0];
  if (half && j < kHin) inps[j] = xn[j];
  if (half && j == kHin) inps[kHin] = s;
  if (tid < 228) hx16[32 + tid] = 0u;            // pairs of fp16 zeros
  if (tid == 0) stor[(size_t)n * kL] = s;
  __syncthreads();

  for (int t = 0; t < kL; ++t) {
    float a0 = half ? 0.f : b1j;   // fma chain A
    float c0 = 0.f;                // fma chain B

    // ---- rows [base, base+64): fp32 AGPR weights; 8 groups of 8 rows ----
    float4 nx0 = *reinterpret_cast<const float4*>(&inps[base]);
    float4 nx1 = *reinterpret_cast<const float4*>(&inps[base + 4]);
    #pragma unroll
    for (int g = 0; g < NAG_H; ++g) {
      const float4 u0 = nx0, u1 = nx1;
      if (g + 1 < NAG_H) {
        nx0 = *reinterpret_cast<const float4*>(&inps[base + 8 * (g + 1)]);
        nx1 = *reinterpret_cast<const float4*>(&inps[base + 8 * (g + 1) + 4]);
      }
      float w0, w1, w2, w3, w4, w5, w6, w7;
      asm volatile(
          "v_accvgpr_read_b32 %0, %8\n\t"
          "v_accvgpr_read_b32 %1, %9\n\t"
          "v_accvgpr_read_b32 %2, %10\n\t"
          "v_accvgpr_read_b32 %3, %11\n\t"
          "v_accvgpr_read_b32 %4, %12\n\t"
          "v_accvgpr_read_b32 %5, %13\n\t"
          "v_accvgpr_read_b32 %6, %14\n\t"
          "v_accvgpr_read_b32 %7, %15"
          : "=v"(w0), "=v"(w1), "=v"(w2), "=v"(w3),
            "=v"(w4), "=v"(w5), "=v"(w6), "=v"(w7)
          : "a"(areg[8 * g + 0]), "a"(areg[8 * g + 1]),
            "a"(areg[8 * g + 2]), "a"(areg[8 * g + 3]),
            "a"(areg[8 * g + 4]), "a"(areg[8 * g + 5]),
            "a"(areg[8 * g + 6]), "a"(areg[8 * g + 7]));
      a0 = fmaf(u0.x, w0, a0); c0 = fmaf(u0.y, w1, c0);
      a0 = fmaf(u0.z, w2, a0); c0 = fmaf(u0.w, w3, c0);
      a0 = fmaf(u1.x, w4, a0); c0 = fmaf(u1.y, w5, c0);
      a0 = fmaf(u1.z, w6, a0); c0 = fmaf(u1.w, w7, c0);
    }

    // ---- rows [base+64, base+128): fp16 LDS pair weights, dot2 ----
    {
      const int m0 = (base + AGP_H) >> 1;   // 32 (half0) / 162 (half1)
      #pragma unroll 4
      for (int u = 0; u < LDSP_H; u += 4) {
        const uint2 ha = *reinterpret_cast<const uint2*>(&hx16[m0 + u]);
        const uint2 hb = *reinterpret_cast<const uint2*>(&hx16[m0 + u + 2]);
        const unsigned wa = wlds16[half * LDSP_H + u + 0][j];
        const unsigned wb = wlds16[half * LDSP_H + u + 1][j];
        const unsigned wc = wlds16[half * LDSP_H + u + 2][j];
        const unsigned wd = wlds16[half * LDSP_H + u + 3][j];
        a0 = dot2h(ha.x, wa, a0); c0 = dot2h(ha.y, wb, c0);
        a0 = dot2h(hb.x, wc, a0); c0 = dot2h(hb.y, wd, c0);
      }
    }

    // ---- rows base+128..base+131: fp32 pinned arch-VGPR weights ----
    {
      const float4 v = *reinterpret_cast<const float4*>(&inps[base + AGP_H + 2 * LDSP_H]);
      a0 = fmaf(v.x, wex0, a0); c0 = fmaf(v.y, wex1, c0);
      a0 = fmaf(v.z, wex2, a0); c0 = fmaf(v.w, wex3, c0);
    }

    // ---- rows [base+132, base+260): streamed fp16, dot2; 16 uint4 chunks ----
    {
      const int ms = (base + AGP_H + 2 * LDSP_H + EXT_H) >> 1;  // 66 / 196
      #pragma unroll 4
      for (int c = 0; c < NSC_H; ++c) {
        const uint4 pk = wpk[(size_t)c * kHid];
        const uint2 ha = *reinterpret_cast<const uint2*>(&hx16[ms + 4 * c]);
        const uint2 hb = *reinterpret_cast<const uint2*>(&hx16[ms + 4 * c + 2]);
        a0 = dot2h(ha.x, pk.x, a0); c0 = dot2h(ha.y, pk.y, c0);
        a0 = dot2h(hb.x, pk.z, a0); c0 = dot2h(hb.y, pk.w, c0);
      }
    }
    if (half) a0 = fmaf(inps[kInp - 1], wtail, a0);  // fp32 tail row 520

    part[half][j] = a0 + c0;
    __syncthreads();  // barrier 2: partials ready; all inps/hx16 reads done

    const float h = tanhf(part[0][j] + part[1][j]);

    // stage next-step inputs that don't depend on o
    if (!half) inps[kHin + 1 + j] = h;
    const float* xr = xn + (size_t)(t + 1) * kHin;
    if (t + 1 < kL && half && j < kHin) inps[j] = xr[j];

    // ---- out = h . W2 + b2 : half0 waves shuffle-reduce ----
    if (!half) {
      float p = h * w2j;
      #pragma unroll
      for (int off = 32; off > 0; off >>= 1) p += __shfl_down(p, off, 64);
      if ((tid & 63) == 0) red[tid >> 6] = p;
    }
    __syncthreads();  // barrier 3: red ready; h/x fully staged in inps

    // restage hx16 from the (next-step) inps: pairs m = 32..259
    if (tid < 228) {
      const int m = 32 + tid;
      const float2 hv = *reinterpret_cast<const float2*>(&inps[2 * m]);
      hx16[m] = pk2h_rne(hv.x, hv.y);
    }

    const float4 r0 = *reinterpret_cast<const float4*>(&red[0]);
    const float4 r1 = *reinterpret_cast<const float4*>(&red[4]);
    const float o = (((r0.x + r0.y) + (r0.z + r0.w)) +
                     ((r1.x + r1.y) + (r1.z + r1.w))) + b2v;  // same in all threads
    if (tid == 0) outp[(size_t)n * kL + t] = o;

    if (t + 1 < kL) {
      s += xr[0] - o;  // replicated identically across all threads
      if (half && j == kHin) inps[kHin] = s;
      if (tid == 0) stor[(size_t)n * kL + t + 1] = s;
    }
    __syncthreads();  // barrier 1 (loop top): next-step inps + hx16 staged
  }
}

extern "C" void kernel_launch(void* const* d_in, const int* in_sizes, int n_in,
                              void* d_out, int out_size, void* d_ws, size_t ws_size,
                              hipStream_t stream) {
  const float* x  = (const float*)d_in[0];
  const float* W1 = (const float*)d_in[1];
  const float* b1 = (const float*)d_in[2];
  const float* W2 = (const float*)d_in[3];
  const float* b2 = (const float*)d_in[4];
  float* out = (float*)d_out;

  // one-time (per launch) repack of streamed W1 rows into packed fp16 form
  {
    const int total = 2 * NSC_H * kHid;           // 16384
    dim3 g((total + 255) / 256), b(256);
    hipLaunchKernelGGL(repack_w1, g, b, 0, stream, W1);
  }

  dim3 grid(kN);          // 256 blocks, 1 batch each, all 256 CUs
  dim3 block(kBlk);       // 1024 threads = 16 waves = 4 waves/SIMD
  hipLaunchKernelGGL(resrnn_fwd, grid, block, 0, stream, x, W1, b1, W2, b2, out);
}

// Round 12
// 3588.849 us; speedup vs baseline: 2.5683x; 1.3064x over previous
//
#include <hip/hip_runtime.h>
#include <hip/hip_fp16.h>
#include <math.h>

// resRNN forward: N=256, L=1024, inp=521 (=8 x + 1 storage + 512 hx), HID=512, OUT=1.
// Round 12: R11 fit = stream 6.8K + ~4.2K non-overlap = 11K cyc/step. On-chip
// capacity was mispartitioned: AGPRs held fp32 rows, but dot2 eats fp16 pairs,
// so the same 64 AGPRs/half now hold 128 rows (packed rne-fp16). Partition per
// half: 128 AGPR-fp16 rows + 56 LDS-fp16 rows + 64/72 streamed-fp16 rows.
// The 17 precision-sensitive rows (x0-7, s, hx0, last 7 hx) stay fp32 in a
// small LDS `wedge` (35 KB). Streamed bytes/step/CU: 262 KB -> 139 KB (~3.6K
// cyc at the measured 38.4 B/cyc/CU L2-stream ceiling).
// Row map (inps index): edge fp32 {0..9, 514..520};
//   half0: AGPR 10..137, LDS 138..193, stream 194..257 (8 chunks)
//   half1: AGPR 258..385, LDS 386..441, stream 442..513 (9 chunks)
// Structure (split-K, 1024 thr, 4 waves/SIMD, 256 blocks, 3 barriers/step)
// unchanged from R9-R11.

constexpr int kN   = 256;
constexpr int kL   = 1024;
constexpr int kHin = 8;
constexpr int kHid = 512;
constexpr int kInp = kHin + 1 + kHid;  // 521
constexpr int kBlk = 1024;

constexpr int AG_P = 64;   // AGPR fp16-pairs per half (= 128 rows)
constexpr int LD_P = 28;   // LDS fp16-pairs per half (= 56 rows)
constexpr int NCH0 = 8;    // streamed 8-row chunks, half0
constexpr int NCH1 = 9;    // streamed 8-row chunks, half1
constexpr int NCHT = NCH0 + NCH1;

constexpr int A0_ROW = 10,  L0_ROW = 138, S0_ROW = 194;
constexpr int A1_ROW = 258, L1_ROW = 386, S1_ROW = 442;
static_assert(A0_ROW + 2 * AG_P == L0_ROW, "");
static_assert(L0_ROW + 2 * LD_P == S0_ROW, "");
static_assert(S0_ROW + 8 * NCH0 == A1_ROW, "");
static_assert(A1_ROW + 2 * AG_P == L1_ROW, "");
static_assert(L1_ROW + 2 * LD_P == S1_ROW, "");
static_assert(S1_ROW + 8 * NCH1 == 514, "");  // rows 514..520 are fp32 edge

// Streamed fp16 weights: g_w1p16[c*512 + j] = rows r0(c)..r0(c)+7 of column j,
// dwords = (even | odd<<16), rne.
__device__ __align__(16) uint4 g_w1p16[NCHT * kHid];

__device__ __forceinline__ unsigned pk2h_rne(float lo, float hi) {
  return (unsigned)__half_as_ushort(__float2half_rn(lo)) |
         ((unsigned)__half_as_ushort(__float2half_rn(hi)) << 16);
}

// d = a.lo*b.lo + a.hi*b.hi + c   (fp16 products exact in f32 accumulate)
__device__ __forceinline__ float dot2h(unsigned a, unsigned b, float c) {
  float d;
  asm("v_dot2_f32_f16 %0, %1, %2, %3" : "=v"(d) : "v"(a), "v"(b), "v"(c));
  return d;
}

__global__ void repack_w1(const float* __restrict__ W1) {
  const int idx = blockIdx.x * 256 + threadIdx.x;
  if (idx >= NCHT * kHid) return;
  const int c = idx >> 9;
  const int j = idx & (kHid - 1);
  const int r = (c < NCH0) ? (S0_ROW + 8 * c) : (S1_ROW + 8 * (c - NCH0));
  uint4 pk;
  pk.x = pk2h_rne(W1[(size_t)(r + 0) * kHid + j], W1[(size_t)(r + 1) * kHid + j]);
  pk.y = pk2h_rne(W1[(size_t)(r + 2) * kHid + j], W1[(size_t)(r + 3) * kHid + j]);
  pk.z = pk2h_rne(W1[(size_t)(r + 4) * kHid + j], W1[(size_t)(r + 5) * kHid + j]);
  pk.w = pk2h_rne(W1[(size_t)(r + 6) * kHid + j], W1[(size_t)(r + 7) * kHid + j]);
  g_w1p16[idx] = pk;
}

__global__
__attribute__((amdgpu_flat_work_group_size(kBlk, kBlk)))
__attribute__((amdgpu_waves_per_eu(4, 4)))
void resrnn_fwd(const float* __restrict__ x, const float* __restrict__ W1,
                const float* __restrict__ b1, const float* __restrict__ W2,
                const float* __restrict__ b2, float* __restrict__ out) {
  // inps: [0..7]=x_t, [8]=s_t, [9..520]=hx_{t-1} (fp32, canonical)
  __shared__ __align__(16) float inps[kInp + 3];
  __shared__ unsigned wlds16[2 * LD_P][kHid];  // fp16 pair weights, 114.7 KB
  __shared__ float wedge[17][kHid];            // fp32 edge-row weights, 34.8 KB
  __shared__ unsigned hx16[260];               // fp16 pairs: hx16[u] = (inps[2u], inps[2u+1])
  __shared__ float part[2][kHid];
  __shared__ __align__(16) float red[8];

  const int tid  = threadIdx.x;
  const int j    = tid & (kHid - 1);   // hidden column
  const int half = tid >> 9;           // K-half
  const int n    = blockIdx.x;         // batch element

  const float b2v = b2[0];
  const float w2j = W2[j];
  const float b1j = b1[j];

  float* const outp = out;
  float* const stor = out + (size_t)kN * kL;

  const float* xn = x + (size_t)n * kL * kHin;
  const float* const wj = W1 + j;      // column j, stride kHid

  // ---- one-time fill ----
  // AGPR: 64 fp16 pairs (= 128 rows)
  unsigned areg[AG_P];
  const int arow = half ? A1_ROW : A0_ROW;
  #pragma unroll
  for (int g = 0; g < AG_P; ++g) {
    const unsigned v = pk2h_rne(wj[(size_t)(arow + 2 * g) * kHid],
                                wj[(size_t)(arow + 2 * g + 1) * kHid]);
    asm volatile("v_accvgpr_write_b32 %0, %1" : "=a"(areg[g]) : "v"(v));
  }
  // LDS: 28 fp16 pairs (= 56 rows)
  const int lrow = half ? L1_ROW : L0_ROW;
  for (int u = 0; u < LD_P; ++u)
    wlds16[half * LD_P + u][j] = pk2h_rne(wj[(size_t)(lrow + 2 * u) * kHid],
                                          wj[(size_t)(lrow + 2 * u + 1) * kHid]);
  // fp32 edge rows: half0 fills rows 0..9, half1 rows 514..520
  if (!half) { for (int k = 0; k < 10; ++k) wedge[k][j] = wj[(size_t)k * kHid]; }
  else       { for (int k = 0; k < 7;  ++k) wedge[10 + k][j] = wj[(size_t)(514 + k) * kHid]; }

  const uint4* const wpk = g_w1p16 + (half ? (size_t)NCH0 * kHid : 0) + j;

  // ---- init: hx = 0, s_0 = x_0[0] ----
  if (!half) inps[kHin + 1 + j] = 0.f;
  float s = xn[0];
  if (half && j < kHin) inps[j] = xn[j];
  if (half && j == kHin) inps[kHin] = s;
  if (tid < 252) hx16[5 + tid] = 0u;
  if (tid == 0) stor[(size_t)n * kL] = s;
  __syncthreads();

  for (int t = 0; t < kL; ++t) {
    float a0 = half ? 0.f : b1j;   // fma chain A
    float c0 = 0.f;                // fma chain B

    // ---- AGPR phase: 8 groups of 8 pairs (128 rows) ----
    const int ub = half ? 129 : 5;   // first hx16 pair of AGPR region
    #pragma unroll
    for (int g = 0; g < 8; ++g) {
      const unsigned h0 = hx16[ub + 8 * g + 0], h1 = hx16[ub + 8 * g + 1];
      const unsigned h2 = hx16[ub + 8 * g + 2], h3 = hx16[ub + 8 * g + 3];
      const unsigned h4 = hx16[ub + 8 * g + 4], h5 = hx16[ub + 8 * g + 5];
      const unsigned h6 = hx16[ub + 8 * g + 6], h7 = hx16[ub + 8 * g + 7];
      unsigned w0, w1, w2, w3, w4, w5, w6, w7;
      asm volatile(
          "v_accvgpr_read_b32 %0, %8\n\t"
          "v_accvgpr_read_b32 %1, %9\n\t"
          "v_accvgpr_read_b32 %2, %10\n\t"
          "v_accvgpr_read_b32 %3, %11\n\t"
          "v_accvgpr_read_b32 %4, %12\n\t"
          "v_accvgpr_read_b32 %5, %13\n\t"
          "v_accvgpr_read_b32 %6, %14\n\t"
          "v_accvgpr_read_b32 %7, %15"
          : "=v"(w0), "=v"(w1), "=v"(w2), "=v"(w3),
            "=v"(w4), "=v"(w5), "=v"(w6), "=v"(w7)
          : "a"(areg[8 * g + 0]), "a"(areg[8 * g + 1]),
            "a"(areg[8 * g + 2]), "a"(areg[8 * g + 3]),
            "a"(areg[8 * g + 4]), "a"(areg[8 * g + 5]),
            "a"(areg[8 * g + 6]), "a"(areg[8 * g + 7]));
      a0 = dot2h(h0, w0, a0); c0 = dot2h(h1, w1, c0);
      a0 = dot2h(h2, w2, a0); c0 = dot2h(h3, w3, c0);
      a0 = dot2h(h4, w4, a0); c0 = dot2h(h5, w5, c0);
      a0 = dot2h(h6, w6, a0); c0 = dot2h(h7, w7, c0);
    }

    // ---- LDS phase: 28 pairs (56 rows) ----
    const int lb = half ? 193 : 69;
    #pragma unroll
    for (int u = 0; u < LD_P; u += 4) {
      const unsigned ha = hx16[lb + u + 0], hb = hx16[lb + u + 1];
      const unsigned hc = hx16[lb + u + 2], hd = hx16[lb + u + 3];
      const unsigned wa = wlds16[half * LD_P + u + 0][j];
      const unsigned wb = wlds16[half * LD_P + u + 1][j];
      const unsigned wc = wlds16[half * LD_P + u + 2][j];
      const unsigned wd = wlds16[half * LD_P + u + 3][j];
      a0 = dot2h(ha, wa, a0); c0 = dot2h(hb, wb, c0);
      a0 = dot2h(hc, wc, a0); c0 = dot2h(hd, wd, c0);
    }

    // ---- streamed phase: 8 (half0) / 9 (half1) uint4 chunks of 8 rows ----
    if (!half) {
      #pragma unroll 4
      for (int c = 0; c < NCH0; ++c) {
        const uint4 pk = wpk[(size_t)c * kHid];
        const int p = 97 + 4 * c;
        const unsigned h0 = hx16[p], h1 = hx16[p + 1], h2 = hx16[p + 2], h3 = hx16[p + 3];
        a0 = dot2h(h0, pk.x, a0); c0 = dot2h(h1, pk.y, c0);
        a0 = dot2h(h2, pk.z, a0); c0 = dot2h(h3, pk.w, c0);
      }
    } else {
      #pragma unroll 3
      for (int c = 0; c < NCH1; ++c) {
        const uint4 pk = wpk[(size_t)c * kHid];
        const int p = 221 + 4 * c;
        const unsigned h0 = hx16[p], h1 = hx16[p + 1], h2 = hx16[p + 2], h3 = hx16[p + 3];
        a0 = dot2h(h0, pk.x, a0); c0 = dot2h(h1, pk.y, c0);
        a0 = dot2h(h2, pk.z, a0); c0 = dot2h(h3, pk.w, c0);
      }
    }

    // ---- fp32 edge rows ----
    if (!half) {
      const float4 vx0 = *reinterpret_cast<const float4*>(&inps[0]);
      const float4 vx1 = *reinterpret_cast<const float4*>(&inps[4]);
      const float vs = inps[8], vh0 = inps[9];
      a0 = fmaf(vx0.x, wedge[0][j], a0); c0 = fmaf(vx0.y, wedge[1][j], c0);
      a0 = fmaf(vx0.z, wedge[2][j], a0); c0 = fmaf(vx0.w, wedge[3][j], c0);
      a0 = fmaf(vx1.x, wedge[4][j], a0); c0 = fmaf(vx1.y, wedge[5][j], c0);
      a0 = fmaf(vx1.z, wedge[6][j], a0); c0 = fmaf(vx1.w, wedge[7][j], c0);
      a0 = fmaf(vs, wedge[8][j], a0);    c0 = fmaf(vh0, wedge[9][j], c0);
    } else {
      const float2 v0 = *reinterpret_cast<const float2*>(&inps[514]);
      const float4 v1 = *reinterpret_cast<const float4*>(&inps[516]);
      const float v2 = inps[520];
      a0 = fmaf(v0.x, wedge[10][j], a0); c0 = fmaf(v0.y, wedge[11][j], c0);
      a0 = fmaf(v1.x, wedge[12][j], a0); c0 = fmaf(v1.y, wedge[13][j], c0);
      a0 = fmaf(v1.z, wedge[14][j], a0); c0 = fmaf(v1.w, wedge[15][j], c0);
      a0 = fmaf(v2, wedge[16][j], a0);
    }

    part[half][j] = a0 + c0;
    __syncthreads();  // barrier 2: partials ready; all inps/hx16 reads done

    const float h = tanhf(part[0][j] + part[1][j]);

    // stage next-step inputs that don't depend on o
    if (!half) inps[kHin + 1 + j] = h;
    const float* xr = xn + (size_t)(t + 1) * kHin;
    if (t + 1 < kL && half && j < kHin) inps[j] = xr[j];

    // ---- out = h . W2 + b2 : half0 waves shuffle-reduce ----
    if (!half) {
      float p = h * w2j;
      #pragma unroll
      for (int off = 32; off > 0; off >>= 1) p += __shfl_down(p, off, 64);
      if ((tid & 63) == 0) red[tid >> 6] = p;
    }
    __syncthreads();  // barrier 3: red ready; h/x fully staged in inps

    // restage hx16 pairs u=5..256 from the (next-step) inps
    if (tid < 252) {
      const int u = 5 + tid;
      hx16[u] = pk2h_rne(inps[2 * u], inps[2 * u + 1]);
    }

    const float4 r0 = *reinterpret_cast<const float4*>(&red[0]);
    const float4 r1 = *reinterpret_cast<const float4*>(&red[4]);
    const float o = (((r0.x + r0.y) + (r0.z + r0.w)) +
                     ((r1.x + r1.y) + (r1.z + r1.w))) + b2v;  // same in all threads
    if (tid == 0) outp[(size_t)n * kL + t] = o;

    if (t + 1 < kL) {
      s += xr[0] - o;  // replicated identically across all threads
      if (half && j == kHin) inps[kHin] = s;
      if (tid == 0) stor[(size_t)n * kL + t + 1] = s;
    }
    __syncthreads();  // barrier 1 (loop top): next-step inps + hx16 staged
  }
}

extern "C" void kernel_launch(void* const* d_in, const int* in_sizes, int n_in,
                              void* d_out, int out_size, void* d_ws, size_t ws_size,
                              hipStream_t stream) {
  const float* x  = (const float*)d_in[0];
  const float* W1 = (const float*)d_in[1];
  const float* b1 = (const float*)d_in[2];
  const float* W2 = (const float*)d_in[3];
  const float* b2 = (const float*)d_in[4];
  float* out = (float*)d_out;

  // one-time (per launch) repack of streamed W1 rows into packed fp16 form
  {
    const int total = NCHT * kHid;                // 8704
    dim3 g((total + 255) / 256), b(256);
    hipLaunchKernelGGL(repack_w1, g, b, 0, stream, W1);
  }

  dim3 grid(kN);          // 256 blocks, 1 batch each, all 256 CUs
  dim3 block(kBlk);       // 1024 threads = 16 waves = 4 waves/SIMD
  hipLaunchKernelGGL(resrnn_fwd, grid, block, 0, stream, x, W1, b1, W2, b2, out);
}